// Round 1
// baseline (490.169 us; speedup 1.0000x reference)
//
#include <hip/hip_runtime.h>

// Apply 4x4 gate U to wires {5,13} of a 26-wire qubit state (2^26 fp32 amps).
// Wire w -> flat-index bit (25-w): wires {5,13} -> bits {20,12}.
// Target digit t = bit20*2 + bit12 (wire 5 is INDEX[0] -> high digit).
//
// v2: each thread processes 8 consecutive rest indices (2x float4 per quadrant
// stream). A wave now covers 2 KiB contiguous per stream (8 streams: 4 read +
// 4 write), halving total waves and per-byte address math, and doubling
// per-thread memory-level parallelism (8 outstanding 16B loads = 128 B).
// All global accesses remain non-temporal: pure streaming, zero reuse.

#define BIT_LO 12u   // wire 13
#define BIT_HI 20u   // wire 5

typedef float v4f __attribute__((ext_vector_type(4)));

__global__ __launch_bounds__(256) void unitary_5_13_kernel(
    const float* __restrict__ x,
    const float* __restrict__ U,
    float* __restrict__ out)
{
    const unsigned tid  = blockIdx.x * blockDim.x + threadIdx.x; // 0 .. 2^21-1
    const unsigned rest = tid << 3;                              // 0 .. 2^24-8, multiple of 8

    // Insert zero bits at positions 12 and 20:
    //   rest bits [0..11]  -> flat bits [0..11]
    //   rest bits [12..18] -> flat bits [13..19]   (<<1)
    //   rest bits [19..23] -> flat bits [21..25]   (<<2)
    // rest%8==0 and the 8-run stays inside bits [0..11], so base..base+7 are
    // contiguous flat indices.
    const unsigned base = (rest & 0x00000FFFu)
                        | ((rest & 0x0007F000u) << 1)
                        | ((rest & 0x00F80000u) << 2);

    const unsigned i0 = base;                                   // bit20=0, bit12=0
    const unsigned i1 = base | (1u << BIT_LO);                  // bit20=0, bit12=1
    const unsigned i2 = base | (1u << BIT_HI);                  // bit20=1, bit12=0
    const unsigned i3 = base | (1u << BIT_HI) | (1u << BIT_LO); // bit20=1, bit12=1

    const v4f* p0 = (const v4f*)(x + i0);
    const v4f* p1 = (const v4f*)(x + i1);
    const v4f* p2 = (const v4f*)(x + i2);
    const v4f* p3 = (const v4f*)(x + i3);

    // Issue all 8 loads up front (compiler schedules one vmcnt drain).
    const v4f a0 = __builtin_nontemporal_load(p0);
    const v4f a1 = __builtin_nontemporal_load(p1);
    const v4f a2 = __builtin_nontemporal_load(p2);
    const v4f a3 = __builtin_nontemporal_load(p3);
    const v4f b0 = __builtin_nontemporal_load(p0 + 1);
    const v4f b1 = __builtin_nontemporal_load(p1 + 1);
    const v4f b2 = __builtin_nontemporal_load(p2 + 1);
    const v4f b3 = __builtin_nontemporal_load(p3 + 1);

    // U is 4x4 row-major; uniform address -> scalar/uniform loads, negligible.
    const float u00 = U[0],  u01 = U[1],  u02 = U[2],  u03 = U[3];
    const float u10 = U[4],  u11 = U[5],  u12 = U[6],  u13 = U[7];
    const float u20 = U[8],  u21 = U[9],  u22 = U[10], u23 = U[11];
    const float u30 = U[12], u31 = U[13], u32 = U[14], u33 = U[15];

    v4f oa0 = u00*a0 + u01*a1 + u02*a2 + u03*a3;
    v4f oa1 = u10*a0 + u11*a1 + u12*a2 + u13*a3;
    v4f oa2 = u20*a0 + u21*a1 + u22*a2 + u23*a3;
    v4f oa3 = u30*a0 + u31*a1 + u32*a2 + u33*a3;

    v4f ob0 = u00*b0 + u01*b1 + u02*b2 + u03*b3;
    v4f ob1 = u10*b0 + u11*b1 + u12*b2 + u13*b3;
    v4f ob2 = u20*b0 + u21*b1 + u22*b2 + u23*b3;
    v4f ob3 = u30*b0 + u31*b1 + u32*b2 + u33*b3;

    v4f* q0 = (v4f*)(out + i0);
    v4f* q1 = (v4f*)(out + i1);
    v4f* q2 = (v4f*)(out + i2);
    v4f* q3 = (v4f*)(out + i3);

    __builtin_nontemporal_store(oa0, q0);
    __builtin_nontemporal_store(oa1, q1);
    __builtin_nontemporal_store(oa2, q2);
    __builtin_nontemporal_store(oa3, q3);
    __builtin_nontemporal_store(ob0, q0 + 1);
    __builtin_nontemporal_store(ob1, q1 + 1);
    __builtin_nontemporal_store(ob2, q2 + 1);
    __builtin_nontemporal_store(ob3, q3 + 1);
}

extern "C" void kernel_launch(void* const* d_in, const int* in_sizes, int n_in,
                              void* d_out, int out_size, void* d_ws, size_t ws_size,
                              hipStream_t stream)
{
    const float* x = (const float*)d_in[0];   // 2^26 fp32 state amplitudes
    const float* U = (const float*)d_in[1];   // 4x4 fp32 gate
    float* out = (float*)d_out;               // 2^26 fp32

    // REST = 2^24 rest indices, 8 per thread -> 2^21 threads
    const int block = 256;
    const int grid  = (1 << 21) / block;      // 8192 blocks
    unitary_5_13_kernel<<<grid, block, 0, stream>>>(x, U, out);
}

// Round 2
// 434.130 us; speedup vs baseline: 1.1291x; 1.1291x over previous
//
#include <hip/hip_runtime.h>

// Apply 4x4 gate U to wires {5,13} of a 26-wire qubit state (2^26 fp32 amps).
// Wire w -> flat-index bit (25-w): wires {5,13} -> bits {20,12}.
// Target digit t = bit20*2 + bit12 (wire 5 is INDEX[0] -> high digit).
//
// v3: identical structure to v2 (8 consecutive rest indices per thread,
// 2x float4 per quadrant stream) but with PLAIN loads/stores instead of
// non-temporal. rocprof on v2 showed WRITE_SIZE = 443 MB for a 268 MB
// output (1.65x write amplification): nt stores bypass L2 write-combining
// and emit partial-line HBM transactions. Plain stores restore full-line
// write-combining; plain loads keep x resident in L3 across iterations
// (L3 was already serving ~43% of reads even with nt hints).

#define BIT_LO 12u   // wire 13
#define BIT_HI 20u   // wire 5

typedef float v4f __attribute__((ext_vector_type(4)));

__global__ __launch_bounds__(256) void unitary_5_13_kernel(
    const float* __restrict__ x,
    const float* __restrict__ U,
    float* __restrict__ out)
{
    const unsigned tid  = blockIdx.x * blockDim.x + threadIdx.x; // 0 .. 2^21-1
    const unsigned rest = tid << 3;                              // 0 .. 2^24-8, multiple of 8

    // Insert zero bits at positions 12 and 20:
    //   rest bits [0..11]  -> flat bits [0..11]
    //   rest bits [12..18] -> flat bits [13..19]   (<<1)
    //   rest bits [19..23] -> flat bits [21..25]   (<<2)
    // rest%8==0 and the 8-run stays inside bits [0..11], so base..base+7 are
    // contiguous flat indices.
    const unsigned base = (rest & 0x00000FFFu)
                        | ((rest & 0x0007F000u) << 1)
                        | ((rest & 0x00F80000u) << 2);

    const unsigned i0 = base;                                   // bit20=0, bit12=0
    const unsigned i1 = base | (1u << BIT_LO);                  // bit20=0, bit12=1
    const unsigned i2 = base | (1u << BIT_HI);                  // bit20=1, bit12=0
    const unsigned i3 = base | (1u << BIT_HI) | (1u << BIT_LO); // bit20=1, bit12=1

    const v4f* p0 = (const v4f*)(x + i0);
    const v4f* p1 = (const v4f*)(x + i1);
    const v4f* p2 = (const v4f*)(x + i2);
    const v4f* p3 = (const v4f*)(x + i3);

    // Issue all 8 loads up front (compiler schedules one vmcnt drain).
    const v4f a0 = p0[0];
    const v4f a1 = p1[0];
    const v4f a2 = p2[0];
    const v4f a3 = p3[0];
    const v4f b0 = p0[1];
    const v4f b1 = p1[1];
    const v4f b2 = p2[1];
    const v4f b3 = p3[1];

    // U is 4x4 row-major; uniform address -> scalar/uniform loads, negligible.
    const float u00 = U[0],  u01 = U[1],  u02 = U[2],  u03 = U[3];
    const float u10 = U[4],  u11 = U[5],  u12 = U[6],  u13 = U[7];
    const float u20 = U[8],  u21 = U[9],  u22 = U[10], u23 = U[11];
    const float u30 = U[12], u31 = U[13], u32 = U[14], u33 = U[15];

    v4f oa0 = u00*a0 + u01*a1 + u02*a2 + u03*a3;
    v4f oa1 = u10*a0 + u11*a1 + u12*a2 + u13*a3;
    v4f oa2 = u20*a0 + u21*a1 + u22*a2 + u23*a3;
    v4f oa3 = u30*a0 + u31*a1 + u32*a2 + u33*a3;

    v4f ob0 = u00*b0 + u01*b1 + u02*b2 + u03*b3;
    v4f ob1 = u10*b0 + u11*b1 + u12*b2 + u13*b3;
    v4f ob2 = u20*b0 + u21*b1 + u22*b2 + u23*b3;
    v4f ob3 = u30*b0 + u31*b1 + u32*b2 + u33*b3;

    v4f* q0 = (v4f*)(out + i0);
    v4f* q1 = (v4f*)(out + i1);
    v4f* q2 = (v4f*)(out + i2);
    v4f* q3 = (v4f*)(out + i3);

    q0[0] = oa0;
    q1[0] = oa1;
    q2[0] = oa2;
    q3[0] = oa3;
    q0[1] = ob0;
    q1[1] = ob1;
    q2[1] = ob2;
    q3[1] = ob3;
}

extern "C" void kernel_launch(void* const* d_in, const int* in_sizes, int n_in,
                              void* d_out, int out_size, void* d_ws, size_t ws_size,
                              hipStream_t stream)
{
    const float* x = (const float*)d_in[0];   // 2^26 fp32 state amplitudes
    const float* U = (const float*)d_in[1];   // 4x4 fp32 gate
    float* out = (float*)d_out;               // 2^26 fp32

    // REST = 2^24 rest indices, 8 per thread -> 2^21 threads
    const int block = 256;
    const int grid  = (1 << 21) / block;      // 8192 blocks
    unitary_5_13_kernel<<<grid, block, 0, stream>>>(x, U, out);
}

// Round 3
// 427.110 us; speedup vs baseline: 1.1476x; 1.0164x over previous
//
#include <hip/hip_runtime.h>

// Apply 4x4 gate U to wires {5,13} of a 26-wire qubit state (2^26 fp32 amps).
// Wire w -> flat-index bit (25-w): wires {5,13} -> bits {20,12}.
// Target digit t = bit20*2 + bit12 (wire 5 is INDEX[0] -> high digit).
//
// v4: plain (cached) loads/stores x 4-floats-per-thread granularity.
// Evidence trail:
//   v0 (nt, 4/thr):    harness 417  -> kernel ~ 92 us (invisible, <164)
//   v2 (nt, 8/thr):    kernel 169 us, WRITE_SIZE 443 MB vs 268 MB output
//                      (nt stores bypass L2 write-combining -> 1.65x write amp)
//   v3 (plain, 8/thr): harness 434  -> kernel ~109 us (invisible, <163)
// Plain stores fix the write amplification; 4/thread doubles waves in flight
// (2^22 threads, 65536 waves) for finer-grained MLP and smoother R/W
// interleave -- for pure streaming at VGPR=32, wave count beats per-thread ILP.

#define BIT_LO 12u   // wire 13
#define BIT_HI 20u   // wire 5

typedef float v4f __attribute__((ext_vector_type(4)));

__global__ __launch_bounds__(256) void unitary_5_13_kernel(
    const float* __restrict__ x,
    const float* __restrict__ U,
    float* __restrict__ out)
{
    const unsigned tid  = blockIdx.x * blockDim.x + threadIdx.x; // 0 .. 2^22-1
    const unsigned rest = tid << 2;                              // 0 .. 2^24-4, multiple of 4

    // Insert zero bits at positions 12 and 20:
    //   rest bits [0..11]  -> flat bits [0..11]
    //   rest bits [12..18] -> flat bits [13..19]   (<<1)
    //   rest bits [19..23] -> flat bits [21..25]   (<<2)
    // rest%4==0 and the 4-run stays inside bits [0..11], so base..base+3 are
    // contiguous flat indices.
    const unsigned base = (rest & 0x00000FFFu)
                        | ((rest & 0x0007F000u) << 1)
                        | ((rest & 0x00F80000u) << 2);

    const unsigned i0 = base;                                   // bit20=0, bit12=0
    const unsigned i1 = base | (1u << BIT_LO);                  // bit20=0, bit12=1
    const unsigned i2 = base | (1u << BIT_HI);                  // bit20=1, bit12=0
    const unsigned i3 = base | (1u << BIT_HI) | (1u << BIT_LO); // bit20=1, bit12=1

    const v4f a0 = *(const v4f*)(x + i0);
    const v4f a1 = *(const v4f*)(x + i1);
    const v4f a2 = *(const v4f*)(x + i2);
    const v4f a3 = *(const v4f*)(x + i3);

    // U is 4x4 row-major; uniform address -> scalar loads, negligible traffic.
    const float u00 = U[0],  u01 = U[1],  u02 = U[2],  u03 = U[3];
    const float u10 = U[4],  u11 = U[5],  u12 = U[6],  u13 = U[7];
    const float u20 = U[8],  u21 = U[9],  u22 = U[10], u23 = U[11];
    const float u30 = U[12], u31 = U[13], u32 = U[14], u33 = U[15];

    v4f o0, o1, o2, o3;
    o0 = u00*a0 + u01*a1 + u02*a2 + u03*a3;
    o1 = u10*a0 + u11*a1 + u12*a2 + u13*a3;
    o2 = u20*a0 + u21*a1 + u22*a2 + u23*a3;
    o3 = u30*a0 + u31*a1 + u32*a2 + u33*a3;

    *(v4f*)(out + i0) = o0;
    *(v4f*)(out + i1) = o1;
    *(v4f*)(out + i2) = o2;
    *(v4f*)(out + i3) = o3;
}

extern "C" void kernel_launch(void* const* d_in, const int* in_sizes, int n_in,
                              void* d_out, int out_size, void* d_ws, size_t ws_size,
                              hipStream_t stream)
{
    const float* x = (const float*)d_in[0];   // 2^26 fp32 state amplitudes
    const float* U = (const float*)d_in[1];   // 4x4 fp32 gate
    float* out = (float*)d_out;               // 2^26 fp32

    // REST = 2^24 rest indices, 4 per thread -> 2^22 threads
    const int block = 256;
    const int grid  = (1 << 22) / block;      // 16384 blocks
    unitary_5_13_kernel<<<grid, block, 0, stream>>>(x, U, out);
}